// Round 8
// baseline (435.476 us; speedup 1.0000x reference)
//
#include <hip/hip_runtime.h>
#include <math.h>

#define TOK 8192
#define DIMN 1024
#define HID 1280
#define NEXP 8
#define NSH 2
#define NSLOT 10
#define RCAP 17408          // 16384 + 8*128 max padding
#define RCAPG (RCAP + 256)  // glist slack for 256-row tiles
#define G1_NT (DIMN / 64)   // 16 K-tiles of 64 for gemm1
#define NGATE (TOK / 4)     // gate blocks

typedef short s16x8 __attribute__((ext_vector_type(8)));
typedef float f32x4 __attribute__((ext_vector_type(4)));

// f32 -> bf16 RNE
__device__ __forceinline__ unsigned short f2bf(float f) {
  unsigned u = __float_as_uint(f);
  u += 0x7fffu + ((u >> 16) & 1u);
  return (unsigned short)(u >> 16);
}
__device__ __forceinline__ float bf2f(unsigned short u) {
  return __uint_as_float((unsigned)u << 16);
}

__device__ __forceinline__ void gl_lds16(const void* g, void* l) {
  typedef __attribute__((address_space(1))) const unsigned int guint;
  typedef __attribute__((address_space(3))) unsigned int luint;
  __builtin_amdgcn_global_load_lds((guint*)g, (luint*)l, 16, 0, 0);
}

// ---------------- init / zero ----------------
__global__ __launch_bounds__(256) void k_zero(int* __restrict__ glist,
                                              int* __restrict__ cnt, int* __restrict__ cnt2) {
  int i = blockIdx.x * 256 + threadIdx.x;
  if (i < RCAPG) glist[i] = 0;
  if (i < NEXP) { cnt[i] = 0; cnt2[i] = 0; }
}

// merged weight convert: r<2560 -> w13b row (interleaved w1/w3 16-col groups); else w2b row
__global__ __launch_bounds__(256) void k_cvt_w(const float* __restrict__ w1, const float* __restrict__ w3,
                                               const float* __restrict__ sw1, const float* __restrict__ sw3,
                                               const float* __restrict__ w2, const float* __restrict__ sw2,
                                               unsigned short* __restrict__ w13b,
                                               unsigned short* __restrict__ w2b) {
  const int r = blockIdx.x;
  const int s = blockIdx.y;
  if (r < 2560) {
    const int which = (r >> 4) & 1;
    const int srow = ((r >> 5) << 4) + (r & 15);
    const float* src;
    if (s < NSH) src = (which ? sw3 : sw1) + ((size_t)s * HID + srow) * DIMN;
    else         src = (which ? w3 : w1) + ((size_t)(s - NSH) * HID + srow) * DIMN;
    unsigned short* dst = w13b + ((size_t)s * 2560 + r) * DIMN;
    int c = threadIdx.x * 4;
    float4 v = *(const float4*)(src + c);
    ushort4 o;
    o.x = f2bf(v.x); o.y = f2bf(v.y); o.z = f2bf(v.z); o.w = f2bf(v.w);
    *(ushort4*)(dst + c) = o;
  } else {
    const int d = r - 2560;
    const float* src = (s < NSH) ? sw2 + ((size_t)s * DIMN + d) * HID
                                 : w2 + ((size_t)(s - NSH) * DIMN + d) * HID;
    unsigned short* dst = w2b + ((size_t)s * DIMN + d) * HID;
    for (int c = threadIdx.x * 4; c < HID; c += 1024) {
      float4 v = *(const float4*)(src + c);
      ushort4 o;
      o.x = f2bf(v.x); o.y = f2bf(v.y); o.z = f2bf(v.z); o.w = f2bf(v.w);
      *(ushort4*)(dst + c) = o;
    }
  }
}

// ---------------- gate (f32 semantics preserved EXACTLY) + xb side-write ----------------
__global__ __launch_bounds__(256) void k_gate(const float* __restrict__ x, const float* __restrict__ emb,
                                              const float* __restrict__ bias,
                                              unsigned short* __restrict__ xb,
                                              int* __restrict__ tidx,
                                              float* __restrict__ tw, float* __restrict__ entp) {
  const int lane = threadIdx.x & 63;
  const int wv = threadIdx.x >> 6;
  const int t = blockIdx.x * 4 + wv;
  const float* xr = x + (size_t)t * DIMN;
  unsigned short* xbr = xb + (size_t)t * DIMN;
  float acc[NEXP];
#pragma unroll
  for (int e = 0; e < NEXP; ++e) acc[e] = 0.0f;
  for (int i = 0; i < DIMN / 64; ++i) {
    float xv = xr[lane + 64 * i];
    xbr[lane + 64 * i] = f2bf(xv);   // fold x->bf16 convert into gate (same values as old k_cvt_x)
#pragma unroll
    for (int e = 0; e < NEXP; ++e)
      acc[e] = fmaf(xv, emb[e * DIMN + lane + 64 * i], acc[e]);
  }
#pragma unroll
  for (int e = 0; e < NEXP; ++e) {
#pragma unroll
    for (int off = 32; off > 0; off >>= 1) acc[e] += __shfl_xor(acc[e], off);
  }
  __shared__ float ebuf[4];
  if (lane == 0) {
    float s[NEXP];
#pragma unroll
    for (int e = 0; e < NEXP; ++e) s[e] = 1.0f / (1.0f + expf(-acc[e])) + bias[e];
    int i0 = 0;
    for (int e = 1; e < NEXP; ++e) if (s[e] > s[i0]) i0 = e;   // strict >: lowest index wins ties
    int i1 = -1;
    for (int e = 0; e < NEXP; ++e) {
      if (e == i0) continue;
      if (i1 < 0 || s[e] > s[i1]) i1 = e;
    }
    float v0 = s[i0], v1 = s[i1];
    float inv = 1.0f / (v0 + v1);
    float w0 = v0 * inv, w1 = v1 * inv;
    tidx[2 * t] = i0; tidx[2 * t + 1] = i1;
    tw[2 * t] = w0; tw[2 * t + 1] = w1;
    ebuf[wv] = -(w0 * logf(w0) + w1 * logf(w1));
  }
  __syncthreads();
  if (threadIdx.x == 0) entp[blockIdx.x] = ebuf[0] + ebuf[1] + ebuf[2] + ebuf[3];
}

// ---------------- count: LDS histogram, 8 global atomics per block ----------------
__global__ __launch_bounds__(256) void k_count(const int* __restrict__ tidx, int* __restrict__ cnt) {
  __shared__ int hist[NEXP];
  const int tid = threadIdx.x;
  if (tid < NEXP) hist[tid] = 0;
  __syncthreads();
  const int t = blockIdx.x * 256 + tid;
  atomicAdd(&hist[tidx[2 * t]], 1);
  atomicAdd(&hist[tidx[2 * t + 1]], 1);
  __syncthreads();
  if (tid < NEXP) atomicAdd(&cnt[tid], hist[tid]);
}

// ---------------- offsets + entropy reduce + tail finalize ----------------
__global__ __launch_bounds__(256) void k_offsets(const int* __restrict__ cnt, int* __restrict__ roff,
                                                 int* __restrict__ cpad, const float* __restrict__ entp,
                                                 float* __restrict__ out_tail) {
  __shared__ float red[256];
  float s = 0.f;
  for (int i = threadIdx.x; i < NGATE; i += 256) s += entp[i];
  red[threadIdx.x] = s;
  __syncthreads();
  for (int st = 128; st > 0; st >>= 1) {
    if (threadIdx.x < st) red[threadIdx.x] += red[threadIdx.x + st];
    __syncthreads();
  }
  if (threadIdx.x == 0) {
    int off = 0;
    for (int e = 0; e < NEXP; ++e) {
      roff[e] = off;
      int cp = (cnt[e] + 127) & ~127;
      cpad[e] = cp;
      off += cp;
    }
    out_tail[0] = 0.f;
    out_tail[1] = red[0] / (float)TOK;
  }
}

// ---------------- scatter: LDS histogram + one range-claim atomic per (block,expert) ----------------
__global__ __launch_bounds__(256) void k_scatter(const int* __restrict__ tidx,
                                                 const int* __restrict__ roff, int* __restrict__ cnt2,
                                                 int* __restrict__ glist, int* __restrict__ pos) {
  __shared__ int hist[NEXP], base[NEXP], cur[NEXP];
  const int tid = threadIdx.x;
  if (tid < NEXP) { hist[tid] = 0; cur[tid] = 0; }
  __syncthreads();
  const int t = blockIdx.x * 256 + tid;
  const int e0 = tidx[2 * t], e1 = tidx[2 * t + 1];
  atomicAdd(&hist[e0], 1);
  atomicAdd(&hist[e1], 1);
  __syncthreads();
  if (tid < NEXP) base[tid] = atomicAdd(&cnt2[tid], hist[tid]);
  __syncthreads();
  int p0 = atomicAdd(&cur[e0], 1);
  int g0 = roff[e0] + base[e0] + p0;
  glist[g0] = t; pos[2 * t] = g0;
  int p1 = atomicAdd(&cur[e1], 1);
  int g1 = roff[e1] + base[e1] + p1;
  glist[g1] = t; pos[2 * t + 1] = g1;
}

// ---------------- GEMM1, 4-phase 256x256x64, READ-AHEAD register pipeline ----------------
// Round-8: ds_reads issue ONE PHASE before their consuming MFMA; NO explicit lgkmcnt
// (compiler emits dependency-exact counted lgkmcnt, leaving the just-issued reads
// outstanding -> LDS drain overlaps the current MFMA cluster). sched_barrier(0) only
// after the two barriers that gate subsequent reads (prevents load-hoist across raw
// s_barrier). Quadrants m0n0->m0n1->m1n1->m1n0; A double-buffered in regs (aregA/aregB),
// B halves cached (breg0 lives ph3->ph0, breg1 ph0->ph2).
__global__ __launch_bounds__(512, 2) void k_gemm1_8ph(const unsigned short* __restrict__ xb,
                                                      const unsigned short* __restrict__ w13b,
                                                      unsigned short* __restrict__ h,
                                                      const int* __restrict__ glist,
                                                      const int* __restrict__ roff,
                                                      const int* __restrict__ cpad) {
  extern __shared__ __align__(16) char smem[];
  const int slot = blockIdx.z, yb = blockIdx.y, bx = blockIdx.x;
  const int tid = threadIdx.x;
  const int w = tid >> 6, lane = tid & 63;
  int hrow0, rowlim;
  int tokq[4];
  const int trbase = w * 8 + (lane >> 3);
  if (slot < NSH) {
    hrow0 = slot * TOK + yb * 256;
    rowlim = 256;
#pragma unroll
    for (int q = 0; q < 4; ++q) tokq[q] = yb * 256 + q * 64 + trbase;
  } else {
    const int e = slot - NSH;
    const int cp = cpad[e];
    if (yb * 256 >= cp) return;
    const int base = roff[e];
    hrow0 = 2 * TOK + base + yb * 256;
    rowlim = cp - yb * 256; if (rowlim > 256) rowlim = 256;
#pragma unroll
    for (int q = 0; q < 4; ++q) tokq[q] = glist[base + yb * 256 + q * 64 + trbase];
  }
  const int srcoff = ((lane & 7) * 16) ^ (((lane >> 4) & 1) << 4) ^ (((lane >> 5) & 1) << 5) ^ ((w & 1) << 6);
  const char* aptr[4];
#pragma unroll
  for (int q = 0; q < 4; ++q) aptr[q] = (const char*)xb + (size_t)tokq[q] * 2048 + srcoff;
  const char* w13s = (const char*)w13b + (size_t)slot * 2560 * 2048;
  const int crow0 = (w >> 2) * 64 + (w & 3) * 8 + (lane >> 3);
  const char* bptr[2];
#pragma unroll
  for (int nq = 0; nq < 2; ++nq)
    bptr[nq] = w13s + (size_t)(bx * 256 + crow0 + nq * 32) * 2048 + srcoff;
  const int dA = (w * 8) * 128;
  const int dB = 32768 + (((w >> 2) * 64 + (w & 3) * 8) * 128);

#define STA(BB, MH, TT) do {                               \
    char* _d = smem + (BB) + dA + (MH) * 8192;             \
    gl_lds16(aptr[MH] + (TT) * 128, _d);                   \
    gl_lds16(aptr[(MH) + 2] + (TT) * 128, _d + 16384);     \
  } while (0)
#define STB(BB, NQ, TT) do {                               \
    char* _d = smem + (BB) + dB + (NQ) * 4096;             \
    gl_lds16(bptr[NQ] + (TT) * 128, _d);                   \
    gl_lds16(bptr[NQ] + 262144 + (TT) * 128, _d + 16384);  \
  } while (0)

  const int lr = lane & 15, lq = lane >> 4;
  const int kswz = (((lr >> 1) & 1) << 4) | (((lr >> 2) & 1) << 5) | (((lr >> 3) & 1) << 6);
  const int wm = w >> 2, wn = w & 3;
  const int aoffb = (wm * 128 + lr) * 128 + lq * 16;
  const int boffb = 32768 + (wn * 64 + lr) * 128 + lq * 16;

#define RD_A(BB, MH, AR) do {                                                                        \
    _Pragma("unroll")                                                                                \
    for (int mf = 0; mf < 4; ++mf)                                                                   \
      _Pragma("unroll")                                                                              \
      for (int ks = 0; ks < 2; ++ks)                                                                 \
        AR[mf][ks] = *(const s16x8*)(smem + (((BB) + aoffb + (MH) * 8192 + mf * 2048 + ks * 64) ^ kswz)); \
  } while (0)
#define RD_B(BB, NQ, RG) do {                                                                        \
    _Pragma("unroll")                                                                                \
    for (int nf = 0; nf < 2; ++nf)                                                                   \
      _Pragma("unroll")                                                                              \
      for (int ks = 0; ks < 2; ++ks)                                                                 \
        RG[nf][ks] = *(const s16x8*)(smem + (((BB) + boffb + (NQ) * 4096 + nf * 2048 + ks * 64) ^ kswz)); \
  } while (0)
#define MFMA16(AR, RG, MH, NQ) do {                                                                  \
    __builtin_amdgcn_s_setprio(1);                                                                   \
    _Pragma("unroll")                                                                                \
    for (int mf = 0; mf < 4; ++mf)                                                                   \
      _Pragma("unroll")                                                                              \
      for (int nf = 0; nf < 2; ++nf)                                                                 \
        _Pragma("unroll")                                                                            \
        for (int ks = 0; ks < 2; ++ks)                                                               \
          acc[(MH) * 4 + mf][(NQ) * 2 + nf] = __builtin_amdgcn_mfma_f32_16x16x32_bf16(               \
              AR[mf][ks], RG[nf][ks], acc[(MH) * 4 + mf][(NQ) * 2 + nf], 0, 0, 0);                   \
    __builtin_amdgcn_s_setprio(0);                                                                   \
  } while (0)
#define VMW(N) asm volatile("s_waitcnt vmcnt(" #N ")" ::: "memory")
#define BARR() __builtin_amdgcn_s_barrier()
#define SCHEDB() __builtin_amdgcn_sched_barrier(0)

  // prologue: tile0 full + tile1 (A0, B0) = 12 loads; VMW(8) retires tile0 A0/B0
  STA(0, 0, 0); STB(0, 0, 0); STA(0, 1, 0); STB(0, 1, 0);
  STA(65536, 0, 1); STB(65536, 0, 1);
  VMW(8);
  BARR(); SCHEDB();
  s16x8 aregA[4][2], aregB[4][2];
  s16x8 breg0[2][2], breg1[2][2];
  RD_A(0, 0, aregA);
  RD_B(0, 0, breg0);

  f32x4 acc[8][4] = {};
  for (int j = 0; j < G1_NT; ++j) {
    const int bufb = (j & 1) << 16;
    const int bufo = bufb ^ 65536;
    const int t1 = (j + 1 < G1_NT) ? j + 1 : G1_NT - 1;  // clamped re-stage keeps vmcnt counts uniform
    const int t2 = (j + 2 < G1_NT) ? j + 2 : G1_NT - 1;
    // ph0 (m0n0): VMW(6) retires A1(j),B1(j); read B1 for ph1 while MFMA uses aregA,breg0
    STA(bufo, 1, t1);
    VMW(6);
    BARR(); SCHEDB();
    RD_B(bufb, 1, breg1);
    MFMA16(aregA, breg0, 0, 0);
    BARR();
    // ph1 (m0n1): read A1 for ph2; MFMA uses aregA,breg1
    STB(bufo, 1, t1);
    BARR();
    RD_A(bufb, 1, aregB);
    MFMA16(aregA, breg1, 0, 1);
    BARR();
    // ph2 (m1n1): no reads; MFMA uses aregB,breg1
    STA(bufb, 0, t2);
    BARR();
    MFMA16(aregB, breg1, 1, 1);
    BARR();
    // ph3 (m1n0): VMW(8) retires A0(j+1),B0(j+1); MFMA first (old breg0), then next-tile reads
    STB(bufb, 0, t2);
    VMW(8);
    BARR(); SCHEDB();
    MFMA16(aregB, breg0, 1, 0);
    RD_A(bufo, 0, aregA);
    RD_B(bufo, 0, breg0);
    BARR();
  }
#undef STA
#undef STB

  asm volatile("s_waitcnt vmcnt(0)" ::: "memory");
  // epilogue: silu(w1col)*w3col -> h (bf16)
#pragma unroll
  for (int m = 0; m < 8; ++m) {
    const int lrow0 = wm * 128 + (m >> 2) * 64 + (m & 3) * 16 + lq * 4;
#pragma unroll
    for (int p = 0; p < 2; ++p) {
      f32x4 a1 = acc[m][2 * p];
      f32x4 a3 = acc[m][2 * p + 1];
      const int hc = (bx * 8 + wn * 2 + p) * 16 + lr;
#pragma unroll
      for (int r = 0; r < 4; ++r) {
        const int lrow = lrow0 + r;
        if (lrow < rowlim) {
          float u = a1[r];
          float hv = (u / (1.f + __expf(-u))) * a3[r];
          h[(size_t)(hrow0 + lrow) * HID + hc] = f2bf(hv);
        }
      }
    }
  }
#undef RD_A
#undef RD_B
#undef MFMA16
#undef VMW
#undef BARR
#undef SCHEDB
}

// ---------------- GEMM2 grouped, 4-phase 256x256x64 (UNCHANGED: control vs gemm1) ----------------
__global__ __launch_bounds__(512, 2) void k_gemm2g(const unsigned short* __restrict__ h,
                                                   const unsigned short* __restrict__ w2b,
                                                   const int* __restrict__ roff,
                                                   const int* __restrict__ cpad,
                                                   float* __restrict__ out,
                                                   unsigned short* __restrict__ ro) {
  extern __shared__ __align__(16) char smem[];
  const int grp = blockIdx.z, bx = blockIdx.x, yb = blockIdx.y;
  const int tid = threadIdx.x;
  const int w = tid >> 6, lane = tid & 63;
  const int trbase = w * 8 + (lane >> 3);
  int nt, rowlim, base = 0;
  size_t arow0, arow1;
  if (grp == 0) {
    if (yb * 256 >= TOK) return;
    nt = 40; rowlim = 256;
    arow0 = (size_t)(yb * 256);
    arow1 = (size_t)(TOK + yb * 256);
  } else {
    const int e = grp - 1;
    const int cp = cpad[e];
    if (yb * 256 >= cp) return;
    base = roff[e];
    nt = 20;
    rowlim = cp - yb * 256; if (rowlim > 256) rowlim = 256;
    arow0 = (size_t)(2 * TOK + base + yb * 256);
    arow1 = arow0;
  }
  const int srcoff = ((lane & 7) * 16) ^ (((lane >> 4) & 1) << 4) ^ (((lane >> 5) & 1) << 5) ^ ((w & 1) << 6);
  const char* aptr0[4];
  const char* aptr1[4];
#pragma unroll
  for (int q = 0; q < 4; ++q) {
    int rq = q * 64 + trbase;
    if (grp != 0 && rq >= rowlim) rq = 0;   // clamp: discarded rows read row 0 (no h overrun)
    aptr0[q] = (const char*)h + (arow0 + rq) * 2560 + srcoff;
    aptr1[q] = (const char*)h + (arow1 + rq) * 2560 + srcoff;
  }
  const int crow0 = (w >> 2) * 64 + (w & 3) * 8 + (lane >> 3);
  const char* bptr0[2];
  const char* bptr1[2];
#pragma unroll
  for (int nq = 0; nq < 2; ++nq) {
    const int bn = bx * 256 + crow0 + nq * 32;
    if (grp == 0) {
      bptr0[nq] = (const char*)w2b + (size_t)bn * 2560 + srcoff;                    // slot 0
      bptr1[nq] = (const char*)w2b + (size_t)(1024 + bn) * 2560 + srcoff;           // slot 1
    } else {
      bptr0[nq] = (const char*)w2b + (size_t)((NSH + grp - 1) * 1024 + bn) * 2560 + srcoff;
      bptr1[nq] = bptr0[nq];
    }
  }
  const int dA = (w * 8) * 128;
  const int dB = 32768 + (((w >> 2) * 64 + (w & 3) * 8) * 128);

#define ASRC(Q, TT) ((TT) < 20 ? aptr0[Q] + (TT) * 128 : aptr1[Q] + ((TT) - 20) * 128)
#define BSRC(NQ, TT) ((TT) < 20 ? bptr0[NQ] + (TT) * 128 : bptr1[NQ] + ((TT) - 20) * 128)
#define STA(BB, MH, TT) do {                               \
    char* _d = smem + (BB) + dA + (MH) * 8192;             \
    gl_lds16(ASRC(MH, TT), _d);                            \
    gl_lds16(ASRC((MH) + 2, TT), _d + 16384);              \
  } while (0)
#define STB(BB, NQ, TT) do {                               \
    char* _d = smem + (BB) + dB + (NQ) * 4096;             \
    gl_lds16(BSRC(NQ, TT), _d);                            \
    gl_lds16(BSRC(NQ, TT) + (size_t)128 * 2560, _d + 16384); \
  } while (0)

  const int lr = lane & 15, lq = lane >> 4;
  const int kswz = (((lr >> 1) & 1) << 4) | (((lr >> 2) & 1) << 5) | (((lr >> 3) & 1) << 6);
  const int wm = w >> 2, wn = w & 3;
  const int aoffb = (wm * 128 + lr) * 128 + lq * 16;
  const int boffb = 32768 + (wn * 64 + lr) * 128 + lq * 16;

#define RD_A(BB, MH) do {                                                                            \
    _Pragma("unroll")                                                                                \
    for (int mf = 0; mf < 4; ++mf)                                                                   \
      _Pragma("unroll")                                                                              \
      for (int ks = 0; ks < 2; ++ks)                                                                 \
        areg[mf][ks] = *(const s16x8*)(smem + (((BB) + aoffb + (MH) * 8192 + mf * 2048 + ks * 64) ^ kswz)); \
  } while (0)
#define RD_B(BB, NQ, RG) do {                                                                        \
    _Pragma("unroll")                                                                                \
    for (int nf = 0; nf < 2; ++nf)                                                                   \
      _Pragma("unroll")                                                                              \
      for (int ks = 0; ks < 2; ++ks)                                                                 \
        RG[nf][ks] = *(const s16x8*)(smem + (((BB) + boffb + (NQ) * 4096 + nf * 2048 + ks * 64) ^ kswz)); \
  } while (0)
#define MFMA16(MH, RG, NQ) do {                                                                      \
    __builtin_amdgcn_s_setprio(1);                                                                   \
    _Pragma("unroll")                                                                                \
    for (int mf = 0; mf < 4; ++mf)                                                                   \
      _Pragma("unroll")                                                                              \
      for (int nf = 0; nf < 2; ++nf)                                                                 \
        _Pragma("unroll")                                                                            \
        for (int ks = 0; ks < 2; ++ks)                                                               \
          acc[(MH) * 4 + mf][(NQ) * 2 + nf] = __builtin_amdgcn_mfma_f32_16x16x32_bf16(               \
              areg[mf][ks], RG[nf][ks], acc[(MH) * 4 + mf][(NQ) * 2 + nf], 0, 0, 0);                 \
    __builtin_amdgcn_s_setprio(0);                                                                   \
  } while (0)
#define VMW(N) asm volatile("s_waitcnt vmcnt(" #N ")" ::: "memory")
#define BARR() __builtin_amdgcn_s_barrier()
#define LGKM0() asm volatile("s_waitcnt lgkmcnt(0)" ::: "memory")

  STA(0, 0, 0); STB(0, 0, 0); STA(0, 1, 0); STB(0, 1, 0);
  STA(65536, 0, 1); STB(65536, 0, 1);
  VMW(8);
  BARR();

  f32x4 acc[8][4] = {};
  for (int j = 0; j < nt; ++j) {
    const int bufb = (j & 1) << 16;
    const int bufo = bufb ^ 65536;
    const int t1 = (j + 1 < nt) ? j + 1 : nt - 1;
    const int t2 = (j + 2 < nt) ? j + 2 : nt - 1;
    s16x8 areg[4][2];
    s16x8 breg0[2][2], breg1[2][2];
    RD_A(bufb, 0);
    RD_B(bufb, 0, breg0);
    STA(bufo, 1, t1);
    VMW(6);
    BARR(); LGKM0();
    MFMA16(0, breg0, 0);
    BARR();
    RD_B(bufb, 1, breg1);
    STB(bufo, 1, t1);
    BARR(); LGKM0();
    MFMA16(0, breg1, 1);
    BARR();
    RD_A(bufb, 1);
    STA(bufb, 0, t2);
    BARR(); LGKM0();
    MFMA16(1, breg1, 1);
    BARR();
    STB(bufb, 0, t2);
    VMW(8);
    BARR();
    MFMA16(1, breg0, 0);
    BARR();
  }
#undef STA
#undef STB
#undef ASRC
#undef BSRC

  asm volatile("s_waitcnt vmcnt(0)" ::: "memory");
  if (grp == 0) {
#pragma unroll
    for (int m = 0; m < 8; ++m) {
      const int lrow0 = wm * 128 + (m >> 2) * 64 + (m & 3) * 16 + lq * 4;
#pragma unroll
      for (int nf = 0; nf < 4; ++nf) {
        const int col = bx * 256 + wn * 64 + nf * 16 + lr;
#pragma unroll
        for (int r = 0; r < 4; ++r)
          out[(size_t)(yb * 256 + lrow0 + r) * DIMN + col] = 0.5f * acc[m][nf][r];
      }
    }
  } else {
#pragma unroll
    for (int m = 0; m < 8; ++m) {
      const int lrow0 = wm * 128 + (m >> 2) * 64 + (m & 3) * 16 + lq * 4;
#pragma unroll
      for (int r = 0; r < 4; ++r) {
        const int lrow = lrow0 + r;
        if (lrow < rowlim) {
          const size_t g = (size_t)(base + yb * 256 + lrow);
#pragma unroll
          for (int nf = 0; nf < 4; ++nf) {
            const int col = bx * 256 + wn * 64 + nf * 16 + lr;
            ro[g * DIMN + col] = f2bf(acc[m][nf][r]);
          }
        }
      }
    }
  }
#undef RD_A
#undef RD_B
#undef MFMA16
#undef VMW
#undef BARR
#undef LGKM0
}

// ---------------- combine: out[t] += w0*ro[g0] + w1*ro[g1] ----------------
__global__ __launch_bounds__(256) void k_combine(const unsigned short* __restrict__ ro,
                                                 const int* __restrict__ pos,
                                                 const float* __restrict__ tw,
                                                 float* __restrict__ out) {
  const int t = blockIdx.x;
  const int g0 = pos[2 * t], g1 = pos[2 * t + 1];
  const float w0 = tw[2 * t], w1 = tw[2 * t + 1];
  const int c = threadIdx.x * 4;
  ushort4 r0 = *(const ushort4*)(ro + (size_t)g0 * DIMN + c);
  ushort4 r1 = *(const ushort4*)(ro + (size_t)g1 * DIMN + c);
  float4 o = *(float4*)(out + (size_t)t * DIMN + c);
  o.x += w0 * bf2f(r0.x) + w1 * bf2f(r1.x);
  o.y += w0 * bf2f(r0.y) + w1 * bf2f(r1.y);
  o.z += w0 * bf2f(r0.z) + w1 * bf2f(r1.z);
  o.w += w0 * bf2f(r0.w) + w1 * bf2f(r1.w);
  *(float4*)(out + (size_t)t * DIMN + c) = o;
}

// ---------------- ws layout ----------------
static const size_t OFF_XB    = 0;
static const size_t OFF_W13   = OFF_XB + (size_t)TOK * DIMN * 2;
static const size_t OFF_W2    = OFF_W13 + (size_t)NSLOT * 2560 * DIMN * 2;
static const size_t OFF_H     = OFF_W2 + (size_t)NSLOT * DIMN * HID * 2;
// ro (RCAPG x DIMN bf16 = 36.2 MB) aliases w13b (52.4 MB): w13b dead after gemm1,
// gemm2g (ro writer) runs strictly after gemm1 in stream order.
static const size_t OFF_RO    = OFF_W13;
static const size_t OFF_GLIST = OFF_H + (size_t)(2 * TOK + RCAP) * HID * 2;
static const size_t OFF_POS   = OFF_GLIST + (size_t)RCAPG * 4;
static const size_t OFF_TIDX  = OFF_POS + (size_t)TOK * 2 * 4;
static const size_t OFF_TW    = OFF_TIDX + (size_t)TOK * 2 * 4;
static const size_t OFF_ENTP  = OFF_TW + (size_t)TOK * 2 * 4;
static const size_t OFF_CNT   = OFF_ENTP + (size_t)NGATE * 4;
static const size_t OFF_CNT2  = OFF_CNT + 32;
static const size_t OFF_ROFF  = OFF_CNT2 + 32;
static const size_t OFF_CPAD  = OFF_ROFF + 32;

extern "C" void kernel_launch(void* const* d_in, const int* in_sizes, int n_in,
                              void* d_out, int out_size, void* d_ws, size_t ws_size,
                              hipStream_t stream) {
  const float* x    = (const float*)d_in[0];
  const float* emb  = (const float*)d_in[1];
  const float* bias = (const float*)d_in[2];
  const float* w1   = (const float*)d_in[3];
  const float* w2   = (const float*)d_in[4];
  const float* w3   = (const float*)d_in[5];
  const float* sw1  = (const float*)d_in[6];
  const float* sw2  = (const float*)d_in[7];
  const float* sw3  = (const float*)d_in[8];
  float* out = (float*)d_out;
  char* ws = (char*)d_ws;
  unsigned short* xb   = (unsigned short*)(ws + OFF_XB);
  unsigned short* w13b = (unsigned short*)(ws + OFF_W13);
  unsigned short* w2b  = (unsigned short*)(ws + OFF_W2);
  unsigned short* h    = (unsigned short*)(ws + OFF_H);
  unsigned short* ro   = (unsigned short*)(ws + OFF_RO);
  int*   glist = (int*)(ws + OFF_GLIST);
  int*   pos   = (int*)(ws + OFF_POS);
  int*   tidx  = (int*)(ws + OFF_TIDX);
  float* tw    = (float*)(ws + OFF_TW);
  float* entp  = (float*)(ws + OFF_ENTP);
  int*   cnt   = (int*)(ws + OFF_CNT);
  int*   cnt2  = (int*)(ws + OFF_CNT2);
  int*   roff  = (int*)(ws + OFF_ROFF);
  int*   cpad  = (int*)(ws + OFF_CPAD);

  hipFuncSetAttribute((const void*)k_gemm1_8ph, hipFuncAttributeMaxDynamicSharedMemorySize, 131072);
  hipFuncSetAttribute((const void*)k_gemm2g, hipFuncAttributeMaxDynamicSharedMemorySize, 131072);

  k_zero<<<(RCAPG + 255) / 256, 256, 0, stream>>>(glist, cnt, cnt2);
  k_cvt_w<<<dim3(2560 + DIMN, NSLOT), 256, 0, stream>>>(w1, w3, sw1, sw3, w2, sw2, w13b, w2b);
  k_gate<<<NGATE, 256, 0, stream>>>(x, emb, bias, xb, tidx, tw, entp);
  k_count<<<TOK / 256, 256, 0, stream>>>(tidx, cnt);
  k_offsets<<<1, 256, 0, stream>>>(cnt, roff, cpad, entp, out + (size_t)TOK * DIMN);
  k_scatter<<<TOK / 256, 256, 0, stream>>>(tidx, roff, cnt2, glist, pos);
  k_gemm1_8ph<<<dim3(10, TOK / 256, NSLOT), 512, 131072, stream>>>(xb, w13b, h, glist, roff, cpad);
  k_gemm2g<<<dim3(DIMN / 256, TOK / 256, 1 + NEXP), 512, 131072, stream>>>(h, w2b, roff, cpad, out, ro);
  k_combine<<<TOK, 256, 0, stream>>>(ro, pos, tw, out);
}

// Round 9
// 423.932 us; speedup vs baseline: 1.0272x; 1.0272x over previous
//
#include <hip/hip_runtime.h>
#include <math.h>

#define TOK 8192
#define DIMN 1024
#define HID 1280
#define NEXP 8
#define NSH 2
#define NSLOT 10
#define RCAP 17408          // 16384 + 8*128 max padding
#define RCAPG (RCAP + 256)  // glist slack for 256-row tiles
#define G1_NT (DIMN / 64)   // 16 K-tiles of 64 for gemm1
#define NGATE (TOK / 4)     // gate blocks

typedef short s16x8 __attribute__((ext_vector_type(8)));
typedef float f32x4 __attribute__((ext_vector_type(4)));

// f32 -> bf16 RNE
__device__ __forceinline__ unsigned short f2bf(float f) {
  unsigned u = __float_as_uint(f);
  u += 0x7fffu + ((u >> 16) & 1u);
  return (unsigned short)(u >> 16);
}
__device__ __forceinline__ float bf2f(unsigned short u) {
  return __uint_as_float((unsigned)u << 16);
}

__device__ __forceinline__ void gl_lds16(const void* g, void* l) {
  typedef __attribute__((address_space(1))) const unsigned int guint;
  typedef __attribute__((address_space(3))) unsigned int luint;
  __builtin_amdgcn_global_load_lds((guint*)g, (luint*)l, 16, 0, 0);
}

// ---------------- init / zero ----------------
__global__ __launch_bounds__(256) void k_zero(int* __restrict__ glist,
                                              int* __restrict__ cnt, int* __restrict__ cnt2) {
  int i = blockIdx.x * 256 + threadIdx.x;
  if (i < RCAPG) glist[i] = 0;
  if (i < NEXP) { cnt[i] = 0; cnt2[i] = 0; }
}

// merged weight convert: r<2560 -> w13b row (interleaved w1/w3 16-col groups); else w2b row
__global__ __launch_bounds__(256) void k_cvt_w(const float* __restrict__ w1, const float* __restrict__ w3,
                                               const float* __restrict__ sw1, const float* __restrict__ sw3,
                                               const float* __restrict__ w2, const float* __restrict__ sw2,
                                               unsigned short* __restrict__ w13b,
                                               unsigned short* __restrict__ w2b) {
  const int r = blockIdx.x;
  const int s = blockIdx.y;
  if (r < 2560) {
    const int which = (r >> 4) & 1;
    const int srow = ((r >> 5) << 4) + (r & 15);
    const float* src;
    if (s < NSH) src = (which ? sw3 : sw1) + ((size_t)s * HID + srow) * DIMN;
    else         src = (which ? w3 : w1) + ((size_t)(s - NSH) * HID + srow) * DIMN;
    unsigned short* dst = w13b + ((size_t)s * 2560 + r) * DIMN;
    int c = threadIdx.x * 4;
    float4 v = *(const float4*)(src + c);
    ushort4 o;
    o.x = f2bf(v.x); o.y = f2bf(v.y); o.z = f2bf(v.z); o.w = f2bf(v.w);
    *(ushort4*)(dst + c) = o;
  } else {
    const int d = r - 2560;
    const float* src = (s < NSH) ? sw2 + ((size_t)s * DIMN + d) * HID
                                 : w2 + ((size_t)(s - NSH) * DIMN + d) * HID;
    unsigned short* dst = w2b + ((size_t)s * DIMN + d) * HID;
    for (int c = threadIdx.x * 4; c < HID; c += 1024) {
      float4 v = *(const float4*)(src + c);
      ushort4 o;
      o.x = f2bf(v.x); o.y = f2bf(v.y); o.z = f2bf(v.z); o.w = f2bf(v.w);
      *(ushort4*)(dst + c) = o;
    }
  }
}

// ---------------- gate (f32 semantics preserved EXACTLY) + xb side-write ----------------
__global__ __launch_bounds__(256) void k_gate(const float* __restrict__ x, const float* __restrict__ emb,
                                              const float* __restrict__ bias,
                                              unsigned short* __restrict__ xb,
                                              int* __restrict__ tidx,
                                              float* __restrict__ tw, float* __restrict__ entp) {
  const int lane = threadIdx.x & 63;
  const int wv = threadIdx.x >> 6;
  const int t = blockIdx.x * 4 + wv;
  const float* xr = x + (size_t)t * DIMN;
  unsigned short* xbr = xb + (size_t)t * DIMN;
  float acc[NEXP];
#pragma unroll
  for (int e = 0; e < NEXP; ++e) acc[e] = 0.0f;
  for (int i = 0; i < DIMN / 64; ++i) {
    float xv = xr[lane + 64 * i];
    xbr[lane + 64 * i] = f2bf(xv);   // fold x->bf16 convert into gate
#pragma unroll
    for (int e = 0; e < NEXP; ++e)
      acc[e] = fmaf(xv, emb[e * DIMN + lane + 64 * i], acc[e]);
  }
#pragma unroll
  for (int e = 0; e < NEXP; ++e) {
#pragma unroll
    for (int off = 32; off > 0; off >>= 1) acc[e] += __shfl_xor(acc[e], off);
  }
  __shared__ float ebuf[4];
  if (lane == 0) {
    float s[NEXP];
#pragma unroll
    for (int e = 0; e < NEXP; ++e) s[e] = 1.0f / (1.0f + expf(-acc[e])) + bias[e];
    int i0 = 0;
    for (int e = 1; e < NEXP; ++e) if (s[e] > s[i0]) i0 = e;   // strict >: lowest index wins ties
    int i1 = -1;
    for (int e = 0; e < NEXP; ++e) {
      if (e == i0) continue;
      if (i1 < 0 || s[e] > s[i1]) i1 = e;
    }
    float v0 = s[i0], v1 = s[i1];
    float inv = 1.0f / (v0 + v1);
    float w0 = v0 * inv, w1 = v1 * inv;
    tidx[2 * t] = i0; tidx[2 * t + 1] = i1;
    tw[2 * t] = w0; tw[2 * t + 1] = w1;
    ebuf[wv] = -(w0 * logf(w0) + w1 * logf(w1));
  }
  __syncthreads();
  if (threadIdx.x == 0) entp[blockIdx.x] = ebuf[0] + ebuf[1] + ebuf[2] + ebuf[3];
}

// ---------------- count: LDS histogram, 8 global atomics per block ----------------
__global__ __launch_bounds__(256) void k_count(const int* __restrict__ tidx, int* __restrict__ cnt) {
  __shared__ int hist[NEXP];
  const int tid = threadIdx.x;
  if (tid < NEXP) hist[tid] = 0;
  __syncthreads();
  const int t = blockIdx.x * 256 + tid;
  atomicAdd(&hist[tidx[2 * t]], 1);
  atomicAdd(&hist[tidx[2 * t + 1]], 1);
  __syncthreads();
  if (tid < NEXP) atomicAdd(&cnt[tid], hist[tid]);
}

// ---------------- offsets + entropy reduce + tail finalize ----------------
__global__ __launch_bounds__(256) void k_offsets(const int* __restrict__ cnt, int* __restrict__ roff,
                                                 int* __restrict__ cpad, const float* __restrict__ entp,
                                                 float* __restrict__ out_tail) {
  __shared__ float red[256];
  float s = 0.f;
  for (int i = threadIdx.x; i < NGATE; i += 256) s += entp[i];
  red[threadIdx.x] = s;
  __syncthreads();
  for (int st = 128; st > 0; st >>= 1) {
    if (threadIdx.x < st) red[threadIdx.x] += red[threadIdx.x + st];
    __syncthreads();
  }
  if (threadIdx.x == 0) {
    int off = 0;
    for (int e = 0; e < NEXP; ++e) {
      roff[e] = off;
      int cp = (cnt[e] + 127) & ~127;
      cpad[e] = cp;
      off += cp;
    }
    out_tail[0] = 0.f;
    out_tail[1] = red[0] / (float)TOK;
  }
}

// ---------------- scatter: LDS histogram + one range-claim atomic per (block,expert) ----------------
__global__ __launch_bounds__(256) void k_scatter(const int* __restrict__ tidx,
                                                 const int* __restrict__ roff, int* __restrict__ cnt2,
                                                 int* __restrict__ glist, int* __restrict__ pos) {
  __shared__ int hist[NEXP], base[NEXP], cur[NEXP];
  const int tid = threadIdx.x;
  if (tid < NEXP) { hist[tid] = 0; cur[tid] = 0; }
  __syncthreads();
  const int t = blockIdx.x * 256 + tid;
  const int e0 = tidx[2 * t], e1 = tidx[2 * t + 1];
  atomicAdd(&hist[e0], 1);
  atomicAdd(&hist[e1], 1);
  __syncthreads();
  if (tid < NEXP) base[tid] = atomicAdd(&cnt2[tid], hist[tid]);
  __syncthreads();
  int p0 = atomicAdd(&cur[e0], 1);
  int g0 = roff[e0] + base[e0] + p0;
  glist[g0] = t; pos[2 * t] = g0;
  int p1 = atomicAdd(&cur[e1], 1);
  int g1 = roff[e1] + base[e1] + p1;
  glist[g1] = t; pos[2 * t + 1] = g1;
}

// ---------------- GEMM1, 4-phase 256x256x64 (round-7 exact: 232us, measured twice) ----------------
// Three inner-loop variants tried (drain-0 fences r4, counted r5, read-ahead r8):
// all 230-250us -> ~745 TF is this structure's rate at K=1024. Do not touch.
__global__ __launch_bounds__(512, 2) void k_gemm1_8ph(const unsigned short* __restrict__ xb,
                                                      const unsigned short* __restrict__ w13b,
                                                      unsigned short* __restrict__ h,
                                                      const int* __restrict__ glist,
                                                      const int* __restrict__ roff,
                                                      const int* __restrict__ cpad) {
  extern __shared__ __align__(16) char smem[];
  const int slot = blockIdx.z, yb = blockIdx.y, bx = blockIdx.x;
  const int tid = threadIdx.x;
  const int w = tid >> 6, lane = tid & 63;
  int hrow0, rowlim;
  int tokq[4];
  const int trbase = w * 8 + (lane >> 3);
  if (slot < NSH) {
    hrow0 = slot * TOK + yb * 256;
    rowlim = 256;
#pragma unroll
    for (int q = 0; q < 4; ++q) tokq[q] = yb * 256 + q * 64 + trbase;
  } else {
    const int e = slot - NSH;
    const int cp = cpad[e];
    if (yb * 256 >= cp) return;
    const int base = roff[e];
    hrow0 = 2 * TOK + base + yb * 256;
    rowlim = cp - yb * 256; if (rowlim > 256) rowlim = 256;
#pragma unroll
    for (int q = 0; q < 4; ++q) tokq[q] = glist[base + yb * 256 + q * 64 + trbase];
  }
  const int srcoff = ((lane & 7) * 16) ^ (((lane >> 4) & 1) << 4) ^ (((lane >> 5) & 1) << 5) ^ ((w & 1) << 6);
  const char* aptr[4];
#pragma unroll
  for (int q = 0; q < 4; ++q) aptr[q] = (const char*)xb + (size_t)tokq[q] * 2048 + srcoff;
  const char* w13s = (const char*)w13b + (size_t)slot * 2560 * 2048;
  const int crow0 = (w >> 2) * 64 + (w & 3) * 8 + (lane >> 3);
  const char* bptr[2];
#pragma unroll
  for (int nq = 0; nq < 2; ++nq)
    bptr[nq] = w13s + (size_t)(bx * 256 + crow0 + nq * 32) * 2048 + srcoff;
  const int dA = (w * 8) * 128;
  const int dB = 32768 + (((w >> 2) * 64 + (w & 3) * 8) * 128);

#define STA(BB, MH, TT) do {                               \
    char* _d = smem + (BB) + dA + (MH) * 8192;             \
    gl_lds16(aptr[MH] + (TT) * 128, _d);                   \
    gl_lds16(aptr[(MH) + 2] + (TT) * 128, _d + 16384);     \
  } while (0)
#define STB(BB, NQ, TT) do {                               \
    char* _d = smem + (BB) + dB + (NQ) * 4096;             \
    gl_lds16(bptr[NQ] + (TT) * 128, _d);                   \
    gl_lds16(bptr[NQ] + 262144 + (TT) * 128, _d + 16384);  \
  } while (0)

  const int lr = lane & 15, lq = lane >> 4;
  const int kswz = (((lr >> 1) & 1) << 4) | (((lr >> 2) & 1) << 5) | (((lr >> 3) & 1) << 6);
  const int wm = w >> 2, wn = w & 3;
  const int aoffb = (wm * 128 + lr) * 128 + lq * 16;
  const int boffb = 32768 + (wn * 64 + lr) * 128 + lq * 16;

#define RD_A(BB, MH) do {                                                                            \
    _Pragma("unroll")                                                                                \
    for (int mf = 0; mf < 4; ++mf)                                                                   \
      _Pragma("unroll")                                                                              \
      for (int ks = 0; ks < 2; ++ks)                                                                 \
        areg[mf][ks] = *(const s16x8*)(smem + (((BB) + aoffb + (MH) * 8192 + mf * 2048 + ks * 64) ^ kswz)); \
  } while (0)
#define RD_B(BB, NQ, RG) do {                                                                        \
    _Pragma("unroll")                                                                                \
    for (int nf = 0; nf < 2; ++nf)                                                                   \
      _Pragma("unroll")                                                                              \
      for (int ks = 0; ks < 2; ++ks)                                                                 \
        RG[nf][ks] = *(const s16x8*)(smem + (((BB) + boffb + (NQ) * 4096 + nf * 2048 + ks * 64) ^ kswz)); \
  } while (0)
#define MFMA16(MH, RG, NQ) do {                                                                      \
    __builtin_amdgcn_s_setprio(1);                                                                   \
    _Pragma("unroll")                                                                                \
    for (int mf = 0; mf < 4; ++mf)                                                                   \
      _Pragma("unroll")                                                                              \
      for (int nf = 0; nf < 2; ++nf)                                                                 \
        _Pragma("unroll")                                                                            \
        for (int ks = 0; ks < 2; ++ks)                                                               \
          acc[(MH) * 4 + mf][(NQ) * 2 + nf] = __builtin_amdgcn_mfma_f32_16x16x32_bf16(               \
              areg[mf][ks], RG[nf][ks], acc[(MH) * 4 + mf][(NQ) * 2 + nf], 0, 0, 0);                 \
    __builtin_amdgcn_s_setprio(0);                                                                   \
  } while (0)
#define VMW(N) asm volatile("s_waitcnt vmcnt(" #N ")" ::: "memory")
#define BARR() __builtin_amdgcn_s_barrier()
#define LGKM0() asm volatile("s_waitcnt lgkmcnt(0)" ::: "memory")

  STA(0, 0, 0); STB(0, 0, 0); STA(0, 1, 0); STB(0, 1, 0);
  STA(65536, 0, 1); STB(65536, 0, 1);
  VMW(8);
  BARR();

  f32x4 acc[8][4] = {};
  for (int j = 0; j < G1_NT; ++j) {
    const int bufb = (j & 1) << 16;
    const int bufo = bufb ^ 65536;
    const int t1 = (j + 1 < G1_NT) ? j + 1 : G1_NT - 1;
    const int t2 = (j + 2 < G1_NT) ? j + 2 : G1_NT - 1;
    s16x8 areg[4][2];
    s16x8 breg0[2][2], breg1[2][2];
    RD_A(bufb, 0);
    RD_B(bufb, 0, breg0);
    STA(bufo, 1, t1);
    VMW(6);
    BARR(); LGKM0();
    MFMA16(0, breg0, 0);
    BARR();
    RD_B(bufb, 1, breg1);
    STB(bufo, 1, t1);
    BARR(); LGKM0();
    MFMA16(0, breg1, 1);
    BARR();
    RD_A(bufb, 1);
    STA(bufb, 0, t2);
    BARR(); LGKM0();
    MFMA16(1, breg1, 1);
    BARR();
    STB(bufb, 0, t2);
    VMW(8);
    BARR();
    MFMA16(1, breg0, 0);
    BARR();
  }
#undef STA
#undef STB

  asm volatile("s_waitcnt vmcnt(0)" ::: "memory");
  // epilogue: silu(w1col)*w3col -> h (bf16)
#pragma unroll
  for (int m = 0; m < 8; ++m) {
    const int lrow0 = wm * 128 + (m >> 2) * 64 + (m & 3) * 16 + lq * 4;
#pragma unroll
    for (int p = 0; p < 2; ++p) {
      f32x4 a1 = acc[m][2 * p];
      f32x4 a3 = acc[m][2 * p + 1];
      const int hc = (bx * 8 + wn * 2 + p) * 16 + lr;
#pragma unroll
      for (int r = 0; r < 4; ++r) {
        const int lrow = lrow0 + r;
        if (lrow < rowlim) {
          float u = a1[r];
          float hv = (u / (1.f + __expf(-u))) * a3[r];
          h[(size_t)(hrow0 + lrow) * HID + hc] = f2bf(hv);
        }
      }
    }
  }
#undef RD_A
#undef RD_B
#undef MFMA16
#undef VMW
#undef BARR
#undef LGKM0
}

// ---------------- GEMM2 grouped, 4-phase 256x256x64 ----------------
__global__ __launch_bounds__(512, 2) void k_gemm2g(const unsigned short* __restrict__ h,
                                                   const unsigned short* __restrict__ w2b,
                                                   const int* __restrict__ roff,
                                                   const int* __restrict__ cpad,
                                                   float* __restrict__ out,
                                                   unsigned short* __restrict__ ro) {
  extern __shared__ __align__(16) char smem[];
  const int grp = blockIdx.z, bx = blockIdx.x, yb = blockIdx.y;
  const int tid = threadIdx.x;
  const int w = tid >> 6, lane = tid & 63;
  const int trbase = w * 8 + (lane >> 3);
  int nt, rowlim, base = 0;
  size_t arow0, arow1;
  if (grp == 0) {
    if (yb * 256 >= TOK) return;
    nt = 40; rowlim = 256;
    arow0 = (size_t)(yb * 256);
    arow1 = (size_t)(TOK + yb * 256);
  } else {
    const int e = grp - 1;
    const int cp = cpad[e];
    if (yb * 256 >= cp) return;
    base = roff[e];
    nt = 20;
    rowlim = cp - yb * 256; if (rowlim > 256) rowlim = 256;
    arow0 = (size_t)(2 * TOK + base + yb * 256);
    arow1 = arow0;
  }
  const int srcoff = ((lane & 7) * 16) ^ (((lane >> 4) & 1) << 4) ^ (((lane >> 5) & 1) << 5) ^ ((w & 1) << 6);
  const char* aptr0[4];
  const char* aptr1[4];
#pragma unroll
  for (int q = 0; q < 4; ++q) {
    int rq = q * 64 + trbase;
    if (grp != 0 && rq >= rowlim) rq = 0;   // clamp: discarded rows read row 0 (no h overrun)
    aptr0[q] = (const char*)h + (arow0 + rq) * 2560 + srcoff;
    aptr1[q] = (const char*)h + (arow1 + rq) * 2560 + srcoff;
  }
  const int crow0 = (w >> 2) * 64 + (w & 3) * 8 + (lane >> 3);
  const char* bptr0[2];
  const char* bptr1[2];
#pragma unroll
  for (int nq = 0; nq < 2; ++nq) {
    const int bn = bx * 256 + crow0 + nq * 32;
    if (grp == 0) {
      bptr0[nq] = (const char*)w2b + (size_t)bn * 2560 + srcoff;                    // slot 0
      bptr1[nq] = (const char*)w2b + (size_t)(1024 + bn) * 2560 + srcoff;           // slot 1
    } else {
      bptr0[nq] = (const char*)w2b + (size_t)((NSH + grp - 1) * 1024 + bn) * 2560 + srcoff;
      bptr1[nq] = bptr0[nq];
    }
  }
  const int dA = (w * 8) * 128;
  const int dB = 32768 + (((w >> 2) * 64 + (w & 3) * 8) * 128);

#define ASRC(Q, TT) ((TT) < 20 ? aptr0[Q] + (TT) * 128 : aptr1[Q] + ((TT) - 20) * 128)
#define BSRC(NQ, TT) ((TT) < 20 ? bptr0[NQ] + (TT) * 128 : bptr1[NQ] + ((TT) - 20) * 128)
#define STA(BB, MH, TT) do {                               \
    char* _d = smem + (BB) + dA + (MH) * 8192;             \
    gl_lds16(ASRC(MH, TT), _d);                            \
    gl_lds16(ASRC((MH) + 2, TT), _d + 16384);              \
  } while (0)
#define STB(BB, NQ, TT) do {                               \
    char* _d = smem + (BB) + dB + (NQ) * 4096;             \
    gl_lds16(BSRC(NQ, TT), _d);                            \
    gl_lds16(BSRC(NQ, TT) + (size_t)128 * 2560, _d + 16384); \
  } while (0)

  const int lr = lane & 15, lq = lane >> 4;
  const int kswz = (((lr >> 1) & 1) << 4) | (((lr >> 2) & 1) << 5) | (((lr >> 3) & 1) << 6);
  const int wm = w >> 2, wn = w & 3;
  const int aoffb = (wm * 128 + lr) * 128 + lq * 16;
  const int boffb = 32768 + (wn * 64 + lr) * 128 + lq * 16;

#define RD_A(BB, MH) do {                                                                            \
    _Pragma("unroll")                                                                                \
    for (int mf = 0; mf < 4; ++mf)                                                                   \
      _Pragma("unroll")                                                                              \
      for (int ks = 0; ks < 2; ++ks)                                                                 \
        areg[mf][ks] = *(const s16x8*)(smem + (((BB) + aoffb + (MH) * 8192 + mf * 2048 + ks * 64) ^ kswz)); \
  } while (0)
#define RD_B(BB, NQ, RG) do {                                                                        \
    _Pragma("unroll")                                                                                \
    for (int nf = 0; nf < 2; ++nf)                                                                   \
      _Pragma("unroll")                                                                              \
      for (int ks = 0; ks < 2; ++ks)                                                                 \
        RG[nf][ks] = *(const s16x8*)(smem + (((BB) + boffb + (NQ) * 4096 + nf * 2048 + ks * 64) ^ kswz)); \
  } while (0)
#define MFMA16(MH, RG, NQ) do {                                                                      \
    __builtin_amdgcn_s_setprio(1);                                                                   \
    _Pragma("unroll")                                                                                \
    for (int mf = 0; mf < 4; ++mf)                                                                   \
      _Pragma("unroll")                                                                              \
      for (int nf = 0; nf < 2; ++nf)                                                                 \
        _Pragma("unroll")                                                                            \
        for (int ks = 0; ks < 2; ++ks)                                                               \
          acc[(MH) * 4 + mf][(NQ) * 2 + nf] = __builtin_amdgcn_mfma_f32_16x16x32_bf16(               \
              areg[mf][ks], RG[nf][ks], acc[(MH) * 4 + mf][(NQ) * 2 + nf], 0, 0, 0);                 \
    __builtin_amdgcn_s_setprio(0);                                                                   \
  } while (0)
#define VMW(N) asm volatile("s_waitcnt vmcnt(" #N ")" ::: "memory")
#define BARR() __builtin_amdgcn_s_barrier()
#define LGKM0() asm volatile("s_waitcnt lgkmcnt(0)" ::: "memory")

  STA(0, 0, 0); STB(0, 0, 0); STA(0, 1, 0); STB(0, 1, 0);
  STA(65536, 0, 1); STB(65536, 0, 1);
  VMW(8);
  BARR();

  f32x4 acc[8][4] = {};
  for (int j = 0; j < nt; ++j) {
    const int bufb = (j & 1) << 16;
    const int bufo = bufb ^ 65536;
    const int t1 = (j + 1 < nt) ? j + 1 : nt - 1;
    const int t2 = (j + 2 < nt) ? j + 2 : nt - 1;
    s16x8 areg[4][2];
    s16x8 breg0[2][2], breg1[2][2];
    RD_A(bufb, 0);
    RD_B(bufb, 0, breg0);
    STA(bufo, 1, t1);
    VMW(6);
    BARR(); LGKM0();
    MFMA16(0, breg0, 0);
    BARR();
    RD_B(bufb, 1, breg1);
    STB(bufo, 1, t1);
    BARR(); LGKM0();
    MFMA16(0, breg1, 1);
    BARR();
    RD_A(bufb, 1);
    STA(bufb, 0, t2);
    BARR(); LGKM0();
    MFMA16(1, breg1, 1);
    BARR();
    STB(bufb, 0, t2);
    VMW(8);
    BARR();
    MFMA16(1, breg0, 0);
    BARR();
  }
#undef STA
#undef STB
#undef ASRC
#undef BSRC

  asm volatile("s_waitcnt vmcnt(0)" ::: "memory");
  if (grp == 0) {
#pragma unroll
    for (int m = 0; m < 8; ++m) {
      const int lrow0 = wm * 128 + (m >> 2) * 64 + (m & 3) * 16 + lq * 4;
#pragma unroll
      for (int nf = 0; nf < 4; ++nf) {
        const int col = bx * 256 + wn * 64 + nf * 16 + lr;
#pragma unroll
        for (int r = 0; r < 4; ++r)
          out[(size_t)(yb * 256 + lrow0 + r) * DIMN + col] = 0.5f * acc[m][nf][r];
      }
    }
  } else {
#pragma unroll
    for (int m = 0; m < 8; ++m) {
      const int lrow0 = wm * 128 + (m >> 2) * 64 + (m & 3) * 16 + lq * 4;
#pragma unroll
      for (int r = 0; r < 4; ++r) {
        const int lrow = lrow0 + r;
        if (lrow < rowlim) {
          const size_t g = (size_t)(base + yb * 256 + lrow);
#pragma unroll
          for (int nf = 0; nf < 4; ++nf) {
            const int col = bx * 256 + wn * 64 + nf * 16 + lr;
            ro[g * DIMN + col] = f2bf(acc[m][nf][r]);
          }
        }
      }
    }
  }
#undef RD_A
#undef RD_B
#undef MFMA16
#undef VMW
#undef BARR
#undef LGKM0
}

// ---------------- combine: out[t] += w0*ro[g0] + w1*ro[g1] ----------------
__global__ __launch_bounds__(256) void k_combine(const unsigned short* __restrict__ ro,
                                                 const int* __restrict__ pos,
                                                 const float* __restrict__ tw,
                                                 float* __restrict__ out) {
  const int t = blockIdx.x;
  const int g0 = pos[2 * t], g1 = pos[2 * t + 1];
  const float w0 = tw[2 * t], w1 = tw[2 * t + 1];
  const int c = threadIdx.x * 4;
  ushort4 r0 = *(const ushort4*)(ro + (size_t)g0 * DIMN + c);
  ushort4 r1 = *(const ushort4*)(ro + (size_t)g1 * DIMN + c);
  float4 o = *(float4*)(out + (size_t)t * DIMN + c);
  o.x += w0 * bf2f(r0.x) + w1 * bf2f(r1.x);
  o.y += w0 * bf2f(r0.y) + w1 * bf2f(r1.y);
  o.z += w0 * bf2f(r0.z) + w1 * bf2f(r1.z);
  o.w += w0 * bf2f(r0.w) + w1 * bf2f(r1.w);
  *(float4*)(out + (size_t)t * DIMN + c) = o;
}

// ---------------- ws layout ----------------
static const size_t OFF_XB    = 0;
static const size_t OFF_W13   = OFF_XB + (size_t)TOK * DIMN * 2;
static const size_t OFF_W2    = OFF_W13 + (size_t)NSLOT * 2560 * DIMN * 2;
static const size_t OFF_H     = OFF_W2 + (size_t)NSLOT * DIMN * HID * 2;
// ro (RCAPG x DIMN bf16 = 36.2 MB) aliases w13b (52.4 MB): w13b dead after gemm1,
// gemm2g (ro writer) runs strictly after gemm1 in stream order.
static const size_t OFF_RO    = OFF_W13;
static const size_t OFF_GLIST = OFF_H + (size_t)(2 * TOK + RCAP) * HID * 2;
static const size_t OFF_POS   = OFF_GLIST + (size_t)RCAPG * 4;
static const size_t OFF_TIDX  = OFF_POS + (size_t)TOK * 2 * 4;
static const size_t OFF_TW    = OFF_TIDX + (size_t)TOK * 2 * 4;
static const size_t OFF_ENTP  = OFF_TW + (size_t)TOK * 2 * 4;
static const size_t OFF_CNT   = OFF_ENTP + (size_t)NGATE * 4;
static const size_t OFF_CNT2  = OFF_CNT + 32;
static const size_t OFF_ROFF  = OFF_CNT2 + 32;
static const size_t OFF_CPAD  = OFF_ROFF + 32;

extern "C" void kernel_launch(void* const* d_in, const int* in_sizes, int n_in,
                              void* d_out, int out_size, void* d_ws, size_t ws_size,
                              hipStream_t stream) {
  const float* x    = (const float*)d_in[0];
  const float* emb  = (const float*)d_in[1];
  const float* bias = (const float*)d_in[2];
  const float* w1   = (const float*)d_in[3];
  const float* w2   = (const float*)d_in[4];
  const float* w3   = (const float*)d_in[5];
  const float* sw1  = (const float*)d_in[6];
  const float* sw2  = (const float*)d_in[7];
  const float* sw3  = (const float*)d_in[8];
  float* out = (float*)d_out;
  char* ws = (char*)d_ws;
  unsigned short* xb   = (unsigned short*)(ws + OFF_XB);
  unsigned short* w13b = (unsigned short*)(ws + OFF_W13);
  unsigned short* w2b  = (unsigned short*)(ws + OFF_W2);
  unsigned short* h    = (unsigned short*)(ws + OFF_H);
  unsigned short* ro   = (unsigned short*)(ws + OFF_RO);
  int*   glist = (int*)(ws + OFF_GLIST);
  int*   pos   = (int*)(ws + OFF_POS);
  int*   tidx  = (int*)(ws + OFF_TIDX);
  float* tw    = (float*)(ws + OFF_TW);
  float* entp  = (float*)(ws + OFF_ENTP);
  int*   cnt   = (int*)(ws + OFF_CNT);
  int*   cnt2  = (int*)(ws + OFF_CNT2);
  int*   roff  = (int*)(ws + OFF_ROFF);
  int*   cpad  = (int*)(ws + OFF_CPAD);

  hipFuncSetAttribute((const void*)k_gemm1_8ph, hipFuncAttributeMaxDynamicSharedMemorySize, 131072);
  hipFuncSetAttribute((const void*)k_gemm2g, hipFuncAttributeMaxDynamicSharedMemorySize, 131072);

  k_zero<<<(RCAPG + 255) / 256, 256, 0, stream>>>(glist, cnt, cnt2);
  k_cvt_w<<<dim3(2560 + DIMN, NSLOT), 256, 0, stream>>>(w1, w3, sw1, sw3, w2, sw2, w13b, w2b);
  k_gate<<<NGATE, 256, 0, stream>>>(x, emb, bias, xb, tidx, tw, entp);
  k_count<<<TOK / 256, 256, 0, stream>>>(tidx, cnt);
  k_offsets<<<1, 256, 0, stream>>>(cnt, roff, cpad, entp, out + (size_t)TOK * DIMN);
  k_scatter<<<TOK / 256, 256, 0, stream>>>(tidx, roff, cnt2, glist, pos);
  k_gemm1_8ph<<<dim3(10, TOK / 256, NSLOT), 512, 131072, stream>>>(xb, w13b, h, glist, roff, cpad);
  k_gemm2g<<<dim3(DIMN / 256, TOK / 256, 1 + NEXP), 512, 131072, stream>>>(h, w2b, roff, cpad, out, ro);
  k_combine<<<TOK, 256, 0, stream>>>(ro, pos, tw, out);
}